// Round 2
// baseline (118136.658 us; speedup 1.0000x reference)
//
#include <hip/hip_runtime.h>
#include <hip/hip_bf16.h>
#include <math.h>

#define BB 256
#define TT 512
#define INW 128
#define EH 512
#define GH 512

#define NGB 32           // blocks per group (column slices of 16)
#define NGRP 8           // batch groups
#define MG 32            // batch rows per group
#define NB 16            // output cols per block

typedef __attribute__((ext_vector_type(8))) short bf16x8;
typedef __attribute__((ext_vector_type(4))) float f32x4;

__device__ __forceinline__ float sigm(float x){ return 1.0f/(1.0f+__expf(-x)); }
__device__ __forceinline__ short f2bf(float x){
    __hip_bfloat16 h = __float2bfloat16(x);
    return *reinterpret_cast<short*>(&h);
}

#define GL2LDS(gp, lp) __builtin_amdgcn_global_load_lds( \
    (const __attribute__((address_space(1))) void*)(gp), \
    (__attribute__((address_space(3))) void*)(lp), 16, 0, 0)

// Cross-block (within batch-group) barrier: monotonic counter, release/acquire agent scope.
__device__ __forceinline__ void grp_sync(unsigned* cnt, unsigned target) {
    __threadfence();
    __syncthreads();
    if (threadIdx.x == 0) {
        __hip_atomic_fetch_add(cnt, 1u, __ATOMIC_RELEASE, __HIP_MEMORY_SCOPE_AGENT);
        long spins = 0;
        while (__hip_atomic_load(cnt, __ATOMIC_RELAXED, __HIP_MEMORY_SCOPE_AGENT) < target) {
            __builtin_amdgcn_s_sleep(1);
            if (++spins > (1L << 22)) break;
        }
    }
    __syncthreads();
    __threadfence();
}

// ================= ENCODER: GRU, weights in register B-frags, h exchanged as bf16 ==============
__global__ __launch_bounds__(512, 1) void enc_kernel(
    const float* __restrict__ src,   // [256][512][128]
    const float* __restrict__ Wi,    // [1536][128] rows r,z,n
    const float* __restrict__ Wh,    // [1536][512]
    short*       __restrict__ hbf,   // [2][256][512] bf16 ping-pong, slot0 zeroed
    float*       __restrict__ hencf, // [256][512] f32 final state
    unsigned*    __restrict__ bars)
{
    __shared__ __align__(16) char sH[32*1024];   // [32][512] bf16, swizzled
    __shared__ __align__(16) char sX[32*256];    // [32][128] bf16, swizzled
    __shared__ float sR[32*17];
    __shared__ float sZ[32*17];
    __shared__ float sHfp[32*17];                // private fp32 h slice [32 rows][16 cols]

    const int bid = blockIdx.x;
    const int g = bid / NGB, ng = bid % NGB;
    const int tid = threadIdx.x;
    const int wid = tid >> 6, lane = tid & 63;
    const int l15 = lane & 15, lk = lane >> 4;
    const int j0 = ng * NB;
    const int b0 = g * MG;
    unsigned* cnt = bars + g * 32;

    // --- persistent register weight fragments (waves 0..5: gate = wid>>1, mtile = wid&1) ---
    bf16x8 whB[16], wxB[4];
    if (wid < 6) {
        const int gate = wid >> 1;   // 0=r 1=z 2=n
        const float* wrh = Wh + (size_t)(gate*EH + j0 + l15) * EH;
        const float* wrx = Wi + (size_t)(gate*EH + j0 + l15) * INW;
        #pragma unroll
        for (int kt = 0; kt < 16; ++kt) {
            int ke = kt*32 + lk*8;
            float4 f0 = *(const float4*)(wrh + ke);
            float4 f1 = *(const float4*)(wrh + ke + 4);
            bf16x8 v;
            v[0]=f2bf(f0.x); v[1]=f2bf(f0.y); v[2]=f2bf(f0.z); v[3]=f2bf(f0.w);
            v[4]=f2bf(f1.x); v[5]=f2bf(f1.y); v[6]=f2bf(f1.z); v[7]=f2bf(f1.w);
            whB[kt] = v;
        }
        #pragma unroll
        for (int kt = 0; kt < 4; ++kt) {
            int ke = kt*32 + lk*8;
            float4 f0 = *(const float4*)(wrx + ke);
            float4 f1 = *(const float4*)(wrx + ke + 4);
            bf16x8 v;
            v[0]=f2bf(f0.x); v[1]=f2bf(f0.y); v[2]=f2bf(f0.z); v[3]=f2bf(f0.w);
            v[4]=f2bf(f1.x); v[5]=f2bf(f1.y); v[6]=f2bf(f1.z); v[7]=f2bf(f1.w);
            wxB[kt] = v;
        }
    }
    { // init private fp32 h = 0
        int row = tid >> 4, col = tid & 15;
        sHfp[row*17 + col] = 0.0f;
    }

    for (int t = 0; t < TT; ++t) {
        const short* hsrc = hbf + (size_t)(t & 1) * BB * EH;
        short*       hdst = hbf + (size_t)((t + 1) & 1) * BB * EH;

        // stage group h (bf16) -> sH : linear LDS dest, pre-swizzled global source
        #pragma unroll
        for (int i = 0; i < 4; ++i) {
            int c = (i*8 + wid)*64 + lane;            // 0..2047 (16B chunks)
            int row = c >> 6;
            int kb  = (c & 63) << 4;
            const char* gp = (const char*)(hsrc + (size_t)(b0 + row)*EH) + (kb ^ ((row & 7) << 4));
            GL2LDS(gp, sH + (size_t)c*16);
        }
        // stage x tile: src[b0..][t][:] fp32 -> bf16, swizzled write
        {
            int e = tid * 8;                // 4096 elems
            int row = e >> 7, k = e & 127;
            const float* sp = src + ((size_t)(b0 + row)*TT + t)*INW + k;
            float4 f0 = *(const float4*)sp;
            float4 f1 = *(const float4*)(sp + 4);
            bf16x8 v;
            v[0]=f2bf(f0.x); v[1]=f2bf(f0.y); v[2]=f2bf(f0.z); v[3]=f2bf(f0.w);
            v[4]=f2bf(f1.x); v[5]=f2bf(f1.y); v[6]=f2bf(f1.z); v[7]=f2bf(f1.w);
            int kb = (k*2) ^ ((row & 7) << 4);
            *(bf16x8*)(sX + row*256 + kb) = v;
        }
        __syncthreads();

        f32x4 acch = {0.f,0.f,0.f,0.f};
        f32x4 accx = {0.f,0.f,0.f,0.f};
        const int m = wid & 1;
        if (wid < 6) {
            const int arow = m*16 + l15;
            const int asw  = (arow & 7) << 4;
            const char* hb = sH + arow*1024;
            const char* xb = sX + arow*256;
            #pragma unroll
            for (int kt = 0; kt < 16; ++kt) {
                int kb = kt*64 + lk*16;
                bf16x8 a = *(const bf16x8*)(hb + (kb ^ asw));
                acch = __builtin_amdgcn_mfma_f32_16x16x32_bf16(a, whB[kt], acch, 0, 0, 0);
            }
            #pragma unroll
            for (int kt = 0; kt < 4; ++kt) {
                int kb = kt*64 + lk*16;
                bf16x8 a = *(const bf16x8*)(xb + (kb ^ asw));
                accx = __builtin_amdgcn_mfma_f32_16x16x32_bf16(a, wxB[kt], accx, 0, 0, 0);
            }
        }
        if (wid < 2) {          // r gate
            #pragma unroll
            for (int v = 0; v < 4; ++v) {
                int row = m*16 + lk*4 + v;
                sR[row*17 + l15] = sigm(accx[v] + acch[v]);
            }
        } else if (wid < 4) {   // z gate
            #pragma unroll
            for (int v = 0; v < 4; ++v) {
                int row = m*16 + lk*4 + v;
                sZ[row*17 + l15] = sigm(accx[v] + acch[v]);
            }
        }
        __syncthreads();
        if (wid == 4 || wid == 5) {   // n gate + combine
            #pragma unroll
            for (int v = 0; v < 4; ++v) {
                int row = m*16 + lk*4 + v;
                float r  = sR[row*17 + l15];
                float z  = sZ[row*17 + l15];
                float n  = tanhf(accx[v] + r * acch[v]);
                float hp = sHfp[row*17 + l15];
                float hn = (1.0f - z)*n + z*hp;
                sHfp[row*17 + l15] = hn;
                hdst[(size_t)(b0 + row)*EH + j0 + l15] = f2bf(hn);
                if (t == TT - 1) hencf[(size_t)(b0 + row)*EH + j0 + l15] = hn;
            }
        }
        grp_sync(cnt, (unsigned)((t + 1) * NGB));
    }
}

// ================= enc2gen linear + reparameterized IC sample =================================
__global__ __launch_bounds__(256) void ic_kernel(
    const float* __restrict__ henc,    // [256][512]
    const float* __restrict__ W,       // [1024][512]
    const float* __restrict__ eps,     // [256][512]
    float*       __restrict__ out_icp, // [256][1024] (output #2)
    float*       __restrict__ gh0f,    // [256][512] f32 generator IC
    short*       __restrict__ gh0b)    // [256][512] bf16 mirror (genH slot0)
{
    __shared__ float hb[EH];
    const int b = blockIdx.x, tid = threadIdx.x;
    for (int k = tid; k < EH; k += 256) hb[k] = henc[(size_t)b*EH + k];
    __syncthreads();

    for (int jj = tid; jj < GH; jj += 256) {
        const float4* wm = (const float4*)(W + (size_t)jj * EH);
        const float4* wl = (const float4*)(W + (size_t)(GH + jj) * EH);
        float am = 0.f, al = 0.f;
        #pragma unroll 4
        for (int k4 = 0; k4 < EH/4; ++k4) {
            float4 h = ((const float4*)hb)[k4];
            float4 a = wm[k4], c = wl[k4];
            am += h.x*a.x + h.y*a.y + h.z*a.z + h.w*a.w;
            al += h.x*c.x + h.y*c.y + h.z*c.z + h.w*c.w;
        }
        out_icp[(size_t)b*2*GH + jj]      = am;
        out_icp[(size_t)b*2*GH + GH + jj] = al;
        float icv = am + __expf(0.5f * al) * eps[(size_t)b*GH + jj];
        gh0f[(size_t)b*GH + jj] = icv;
        gh0b[(size_t)b*GH + jj] = f2bf(icv);
    }
}

// ================= GENERATOR: modified GRU cell, 2 phases/step ================================
__global__ __launch_bounds__(512, 1) void gen_kernel(
    const float* __restrict__ Wru,   // [1024][512] rows r then u
    const float* __restrict__ Wc,    // [512][512]
    const float* __restrict__ gh0f,  // [256][512] f32 ic
    short*       __restrict__ hbf,   // [2][256][512] bf16 ping-pong (slot0 = ic mirror)
    short*       __restrict__ rhbf,  // [8][32][512] bf16 r*h exchange
    float*       __restrict__ out,   // [256][512][512] (output #1)
    unsigned*    __restrict__ bars)
{
    __shared__ __align__(16) char sH[32*1024];   // h or rh tile [32][512] bf16, swizzled
    __shared__ float sU[32*17];
    __shared__ float sHfp[32*17];

    const int bid = blockIdx.x;
    const int g = bid / NGB, ng = bid % NGB;
    const int tid = threadIdx.x;
    const int wid = tid >> 6, lane = tid & 63;
    const int l15 = lane & 15, lk = lane >> 4;
    const int j0 = ng * NB;
    const int b0 = g * MG;
    unsigned* cnt = bars + g * 32;
    short* rhg = rhbf + (size_t)g * MG * GH;

    // persistent weight fragments: waves 0,1 -> r rows; 2,3 -> u rows; 4,5 -> c rows
    bf16x8 wB[16];
    if (wid < 6) {
        const float* wr;
        if (wid < 2)      wr = Wru + (size_t)(j0 + l15) * GH;
        else if (wid < 4) wr = Wru + (size_t)(GH + j0 + l15) * GH;
        else              wr = Wc  + (size_t)(j0 + l15) * GH;
        #pragma unroll
        for (int kt = 0; kt < 16; ++kt) {
            int ke = kt*32 + lk*8;
            float4 f0 = *(const float4*)(wr + ke);
            float4 f1 = *(const float4*)(wr + ke + 4);
            bf16x8 v;
            v[0]=f2bf(f0.x); v[1]=f2bf(f0.y); v[2]=f2bf(f0.z); v[3]=f2bf(f0.w);
            v[4]=f2bf(f1.x); v[5]=f2bf(f1.y); v[6]=f2bf(f1.z); v[7]=f2bf(f1.w);
            wB[kt] = v;
        }
    }
    { // private fp32 h slice init from ic
        int row = tid >> 4, col = tid & 15;
        sHfp[row*17 + col] = gh0f[(size_t)(b0 + row)*GH + j0 + col];
    }

    for (int t = 0; t < TT; ++t) {
        const short* hsrc = hbf + (size_t)(t & 1) * BB * GH;
        short*       hdst = hbf + (size_t)((t + 1) & 1) * BB * GH;

        // stage group h bf16 -> sH
        #pragma unroll
        for (int i = 0; i < 4; ++i) {
            int c = (i*8 + wid)*64 + lane;
            int row = c >> 6;
            int kb  = (c & 63) << 4;
            const char* gp = (const char*)(hsrc + (size_t)(b0 + row)*GH) + (kb ^ ((row & 7) << 4));
            GL2LDS(gp, sH + (size_t)c*16);
        }
        __syncthreads();

        // phase 1 (waves 0-3): r (0,1) and u (2,3)
        if (wid < 4) {
            const int m = wid & 1;
            const int arow = m*16 + l15;
            const int asw  = (arow & 7) << 4;
            const char* hb = sH + arow*1024;
            f32x4 acc = {0.f,0.f,0.f,0.f};
            #pragma unroll
            for (int kt = 0; kt < 16; ++kt) {
                int kb = kt*64 + lk*16;
                bf16x8 a = *(const bf16x8*)(hb + (kb ^ asw));
                acc = __builtin_amdgcn_mfma_f32_16x16x32_bf16(a, wB[kt], acc, 0, 0, 0);
            }
            if (wid < 2) {
                #pragma unroll
                for (int v = 0; v < 4; ++v) {
                    int row = m*16 + lk*4 + v;
                    float hp = sHfp[row*17 + l15];
                    float rv = sigm(acc[v]);
                    rhg[(size_t)row*GH + j0 + l15] = f2bf(rv * hp);
                }
            } else {
                #pragma unroll
                for (int v = 0; v < 4; ++v) {
                    int row = m*16 + lk*4 + v;
                    sU[row*17 + l15] = sigm(acc[v] + 1.0f);
                }
            }
        }
        grp_sync(cnt, (unsigned)((2*t + 1) * NGB));

        // stage rh -> sH (reuse)
        #pragma unroll
        for (int i = 0; i < 4; ++i) {
            int c = (i*8 + wid)*64 + lane;
            int row = c >> 6;
            int kb  = (c & 63) << 4;
            const char* gp = (const char*)(rhg + (size_t)row*GH) + (kb ^ ((row & 7) << 4));
            GL2LDS(gp, sH + (size_t)c*16);
        }
        __syncthreads();

        // phase 2 (waves 4,5): candidate + combine
        if (wid == 4 || wid == 5) {
            const int m = wid & 1;
            const int arow = m*16 + l15;
            const int asw  = (arow & 7) << 4;
            const char* hb = sH + arow*1024;
            f32x4 acc = {0.f,0.f,0.f,0.f};
            #pragma unroll
            for (int kt = 0; kt < 16; ++kt) {
                int kb = kt*64 + lk*16;
                bf16x8 a = *(const bf16x8*)(hb + (kb ^ asw));
                acc = __builtin_amdgcn_mfma_f32_16x16x32_bf16(a, wB[kt], acc, 0, 0, 0);
            }
            #pragma unroll
            for (int v = 0; v < 4; ++v) {
                int row = m*16 + lk*4 + v;
                float cv = tanhf(acc[v]);
                float u  = sU[row*17 + l15];
                float hp = sHfp[row*17 + l15];
                float hn = u*hp + (1.0f - u)*cv;
                sHfp[row*17 + l15] = hn;
                hdst[(size_t)(b0 + row)*GH + j0 + l15] = f2bf(hn);
                out[((size_t)(b0 + row)*TT + t)*GH + j0 + l15] = fminf(fmaxf(hn, -5.0f), 5.0f);
            }
        }
        grp_sync(cnt, (unsigned)((2*t + 2) * NGB));
    }
}

extern "C" void kernel_launch(void* const* d_in, const int* in_sizes, int n_in,
                              void* d_out, int out_size, void* d_ws, size_t ws_size,
                              hipStream_t stream) {
    (void)in_sizes; (void)n_in; (void)out_size; (void)ws_size;

    const float* src    = (const float*)d_in[0];
    const float* eps    = (const float*)d_in[1];
    const float* enc_Wi = (const float*)d_in[2];
    const float* enc_Wh = (const float*)d_in[3];
    const float* e2g    = (const float*)d_in[4];
    const float* gWru   = (const float*)d_in[5];
    const float* gWc    = (const float*)d_in[6];
    float* out = (float*)d_out;

    // workspace layout (~2.26 MB):
    char* ws = (char*)d_ws;
    unsigned* bars = (unsigned*)ws;                          // 8 KB (enc @0, gen @+4KB)
    float* hencf = (float*)(ws + 8192);                      // 512 KB [256][512] f32
    float* gh0f  = (float*)(ws + 8192 + 512*1024);           // 512 KB [256][512] f32
    short* encH  = (short*)(ws + 8192 + 1024*1024);          // 512 KB [2][256][512] bf16
    short* genH  = (short*)(ws + 8192 + 1536*1024);          // 512 KB [2][256][512] bf16
    short* rhbf  = (short*)(ws + 8192 + 2048*1024);          // 256 KB [8][32][512] bf16

    hipMemsetAsync(bars, 0, 8192, stream);
    hipMemsetAsync(encH, 0, (size_t)BB*EH*2, stream);        // enc h0 = 0 (slot 0)

    enc_kernel<<<dim3(256), dim3(512), 0, stream>>>(src, enc_Wi, enc_Wh, encH, hencf, bars);
    ic_kernel <<<dim3(256), dim3(256), 0, stream>>>(hencf, e2g, eps,
                                                    out + (size_t)BB*TT*GH, gh0f, genH);
    gen_kernel<<<dim3(256), dim3(512), 0, stream>>>(gWru, gWc, gh0f, genH, rhbf, out,
                                                    bars + 1024);
}

// Round 3
// 5690.678 us; speedup vs baseline: 20.7597x; 20.7597x over previous
//
#include <hip/hip_runtime.h>
#include <hip/hip_bf16.h>
#include <math.h>

#define BB 256
#define TT 512
#define INW 128
#define EH 512
#define GH 512

#define NGB 32           // blocks per group (column slices of 16)
#define NGRP 8           // batch groups
#define MG 32            // batch rows per group
#define NB 16            // output cols per block

typedef __attribute__((ext_vector_type(8))) short bf16x8;
typedef __attribute__((ext_vector_type(4))) float f32x4;
typedef __attribute__((ext_vector_type(2))) unsigned long long u64x2;

__device__ __forceinline__ float sigm(float x){ return 1.0f/(1.0f+__expf(-x)); }
__device__ __forceinline__ short f2bf(float x){
    __hip_bfloat16 h = __float2bfloat16(x);
    return *reinterpret_cast<short*>(&h);
}

// IC-coherent (agent-scope, relaxed) data path: bypasses non-coherent L1/L2,
// no cache-wide fences. Ordering is done with s_waitcnt + counter atomics.
__device__ __forceinline__ unsigned long long ld_coh64(const unsigned long long* p){
    return __hip_atomic_load(p, __ATOMIC_RELAXED, __HIP_MEMORY_SCOPE_AGENT);
}
__device__ __forceinline__ void st_coh32(unsigned* p, unsigned v){
    __hip_atomic_store(p, v, __ATOMIC_RELAXED, __HIP_MEMORY_SCOPE_AGENT);
}

// Cross-block barrier WITHOUT agent fences: prior coherent stores are at the
// coherence point once vmcnt drains; counter add (relaxed) serializes after.
__device__ __forceinline__ void grp_sync(unsigned* cnt, unsigned target) {
    asm volatile("s_waitcnt vmcnt(0)" ::: "memory");
    __syncthreads();
    if (threadIdx.x == 0) {
        __hip_atomic_fetch_add(cnt, 1u, __ATOMIC_RELAXED, __HIP_MEMORY_SCOPE_AGENT);
        long spins = 0;
        while (__hip_atomic_load(cnt, __ATOMIC_RELAXED, __HIP_MEMORY_SCOPE_AGENT) < target) {
            __builtin_amdgcn_s_sleep(1);
            if (++spins > (1L << 22)) break;   // escape hatch, never hit legitimately
        }
    }
    __syncthreads();
}

// pack this lane's bf16 (col j0+l15) with lane^1's into a u32, even lane stores
__device__ __forceinline__ void pack_store_bf(unsigned* dst_even, short bv, int l15){
    unsigned mine = (unsigned short)bv;
    unsigned othr = __shfl_xor(mine, 1);
    if (!(l15 & 1)) st_coh32(dst_even, (othr << 16) | mine);
}

// ================= ENCODER: GRU, weights in register B-frags, h exchanged coherently ==========
__global__ __launch_bounds__(512, 1) void enc_kernel(
    const float* __restrict__ src,   // [256][512][128]
    const float* __restrict__ Wi,    // [1536][128] rows r,z,n
    const float* __restrict__ Wh,    // [1536][512]
    short*       __restrict__ hbf,   // [2][256][512] bf16 ping-pong, slot0 zeroed
    float*       __restrict__ hencf, // [256][512] f32 final state
    unsigned*    __restrict__ bars)
{
    __shared__ __align__(16) char sH[32*1024];   // [32][512] bf16, swizzled
    __shared__ __align__(16) char sX[32*256];    // [32][128] bf16, swizzled
    __shared__ float sR[32*17];
    __shared__ float sZ[32*17];
    __shared__ float sHfp[32*17];                // private fp32 h slice [32 rows][16 cols]

    const int bid = blockIdx.x;
    const int g = bid / NGB, ng = bid % NGB;
    const int tid = threadIdx.x;
    const int wid = tid >> 6, lane = tid & 63;
    const int l15 = lane & 15, lk = lane >> 4;
    const int j0 = ng * NB;
    const int b0 = g * MG;
    unsigned* cnt = bars + g * 32;

    // persistent register weight fragments (waves 0..5: gate = wid>>1, mtile = wid&1)
    bf16x8 whB[16], wxB[4];
    if (wid < 6) {
        const int gate = wid >> 1;   // 0=r 1=z 2=n
        const float* wrh = Wh + (size_t)(gate*EH + j0 + l15) * EH;
        const float* wrx = Wi + (size_t)(gate*EH + j0 + l15) * INW;
        #pragma unroll
        for (int kt = 0; kt < 16; ++kt) {
            int ke = kt*32 + lk*8;
            float4 f0 = *(const float4*)(wrh + ke);
            float4 f1 = *(const float4*)(wrh + ke + 4);
            bf16x8 v;
            v[0]=f2bf(f0.x); v[1]=f2bf(f0.y); v[2]=f2bf(f0.z); v[3]=f2bf(f0.w);
            v[4]=f2bf(f1.x); v[5]=f2bf(f1.y); v[6]=f2bf(f1.z); v[7]=f2bf(f1.w);
            whB[kt] = v;
        }
        #pragma unroll
        for (int kt = 0; kt < 4; ++kt) {
            int ke = kt*32 + lk*8;
            float4 f0 = *(const float4*)(wrx + ke);
            float4 f1 = *(const float4*)(wrx + ke + 4);
            bf16x8 v;
            v[0]=f2bf(f0.x); v[1]=f2bf(f0.y); v[2]=f2bf(f0.z); v[3]=f2bf(f0.w);
            v[4]=f2bf(f1.x); v[5]=f2bf(f1.y); v[6]=f2bf(f1.z); v[7]=f2bf(f1.w);
            wxB[kt] = v;
        }
    }
    {
        int row = tid >> 4, col = tid & 15;
        sHfp[row*17 + col] = 0.0f;
    }

    for (int t = 0; t < TT; ++t) {
        const short* hsrc = hbf + (size_t)(t & 1) * BB * EH;
        short*       hdst = hbf + (size_t)((t + 1) & 1) * BB * EH;

        // stage group h (bf16) -> sH: coherent u64 loads, swizzled ds_write_b128
        #pragma unroll
        for (int i = 0; i < 4; ++i) {
            int row = i*8 + wid;
            int kb  = lane << 4;
            const unsigned long long* gp =
                (const unsigned long long*)((const char*)(hsrc + (size_t)(b0 + row)*EH) + kb);
            unsigned long long v0 = ld_coh64(gp);
            unsigned long long v1 = ld_coh64(gp + 1);
            u64x2 v; v[0] = v0; v[1] = v1;
            *(u64x2*)(sH + row*1024 + (kb ^ ((row & 7) << 4))) = v;
        }
        // stage x tile: src fp32 -> bf16, swizzled write (read-only input, plain loads)
        {
            int e = tid * 8;
            int row = e >> 7, k = e & 127;
            const float* sp = src + ((size_t)(b0 + row)*TT + t)*INW + k;
            float4 f0 = *(const float4*)sp;
            float4 f1 = *(const float4*)(sp + 4);
            bf16x8 v;
            v[0]=f2bf(f0.x); v[1]=f2bf(f0.y); v[2]=f2bf(f0.z); v[3]=f2bf(f0.w);
            v[4]=f2bf(f1.x); v[5]=f2bf(f1.y); v[6]=f2bf(f1.z); v[7]=f2bf(f1.w);
            int kb = (k*2) ^ ((row & 7) << 4);
            *(bf16x8*)(sX + row*256 + kb) = v;
        }
        __syncthreads();

        f32x4 acch = {0.f,0.f,0.f,0.f};
        f32x4 accx = {0.f,0.f,0.f,0.f};
        const int m = wid & 1;
        if (wid < 6) {
            const int arow = m*16 + l15;
            const int asw  = (arow & 7) << 4;
            const char* hb = sH + arow*1024;
            const char* xb = sX + arow*256;
            #pragma unroll
            for (int kt = 0; kt < 16; ++kt) {
                int kb = kt*64 + lk*16;
                bf16x8 a = *(const bf16x8*)(hb + (kb ^ asw));
                acch = __builtin_amdgcn_mfma_f32_16x16x32_bf16(a, whB[kt], acch, 0, 0, 0);
            }
            #pragma unroll
            for (int kt = 0; kt < 4; ++kt) {
                int kb = kt*64 + lk*16;
                bf16x8 a = *(const bf16x8*)(xb + (kb ^ asw));
                accx = __builtin_amdgcn_mfma_f32_16x16x32_bf16(a, wxB[kt], accx, 0, 0, 0);
            }
        }
        if (wid < 2) {          // r gate
            #pragma unroll
            for (int v = 0; v < 4; ++v) {
                int row = m*16 + lk*4 + v;
                sR[row*17 + l15] = sigm(accx[v] + acch[v]);
            }
        } else if (wid < 4) {   // z gate
            #pragma unroll
            for (int v = 0; v < 4; ++v) {
                int row = m*16 + lk*4 + v;
                sZ[row*17 + l15] = sigm(accx[v] + acch[v]);
            }
        }
        __syncthreads();
        if (wid == 4 || wid == 5) {   // n gate + combine + coherent packed store
            #pragma unroll
            for (int v = 0; v < 4; ++v) {
                int row = m*16 + lk*4 + v;
                float r  = sR[row*17 + l15];
                float z  = sZ[row*17 + l15];
                float n  = tanhf(accx[v] + r * acch[v]);
                float hp = sHfp[row*17 + l15];
                float hn = (1.f - z)*n + z*hp;
                sHfp[row*17 + l15] = hn;
                unsigned* dst = (unsigned*)&hdst[(size_t)(b0 + row)*EH + j0 + (l15 & ~1)];
                pack_store_bf(dst, f2bf(hn), l15);
                if (t == TT - 1) hencf[(size_t)(b0 + row)*EH + j0 + l15] = hn;
            }
        }
        grp_sync(cnt, (unsigned)((t + 1) * NGB));
    }
}

// ================= enc2gen linear + reparameterized IC sample =================================
__global__ __launch_bounds__(256) void ic_kernel(
    const float* __restrict__ henc,    // [256][512]
    const float* __restrict__ W,       // [1024][512]
    const float* __restrict__ eps,     // [256][512]
    float*       __restrict__ out_icp, // [256][1024] (output #2)
    float*       __restrict__ gh0f,    // [256][512] f32 generator IC
    short*       __restrict__ gh0b)    // [256][512] bf16 mirror (genH slot0)
{
    __shared__ float hb[EH];
    const int b = blockIdx.x, tid = threadIdx.x;
    for (int k = tid; k < EH; k += 256) hb[k] = henc[(size_t)b*EH + k];
    __syncthreads();

    for (int jj = tid; jj < GH; jj += 256) {
        const float4* wm = (const float4*)(W + (size_t)jj * EH);
        const float4* wl = (const float4*)(W + (size_t)(GH + jj) * EH);
        float am = 0.f, al = 0.f;
        #pragma unroll 4
        for (int k4 = 0; k4 < EH/4; ++k4) {
            float4 h = ((const float4*)hb)[k4];
            float4 a = wm[k4], c = wl[k4];
            am += h.x*a.x + h.y*a.y + h.z*a.z + h.w*a.w;
            al += h.x*c.x + h.y*c.y + h.z*c.z + h.w*c.w;
        }
        out_icp[(size_t)b*2*GH + jj]      = am;
        out_icp[(size_t)b*2*GH + GH + jj] = al;
        float icv = am + __expf(0.5f * al) * eps[(size_t)b*GH + jj];
        gh0f[(size_t)b*GH + jj] = icv;
        gh0b[(size_t)b*GH + jj] = f2bf(icv);
    }
}

// ================= GENERATOR: modified GRU cell, 2 phases/step ================================
__global__ __launch_bounds__(512, 1) void gen_kernel(
    const float* __restrict__ Wru,   // [1024][512] rows r then u
    const float* __restrict__ Wc,    // [512][512]
    const float* __restrict__ gh0f,  // [256][512] f32 ic
    short*       __restrict__ hbf,   // [2][256][512] bf16 ping-pong (slot0 = ic mirror)
    short*       __restrict__ rhbf,  // [8][32][512] bf16 r*h exchange
    float*       __restrict__ out,   // [256][512][512] (output #1)
    unsigned*    __restrict__ bars)
{
    __shared__ __align__(16) char sH[32*1024];   // h or rh tile [32][512] bf16, swizzled
    __shared__ float sU[32*17];
    __shared__ float sHfp[32*17];

    const int bid = blockIdx.x;
    const int g = bid / NGB, ng = bid % NGB;
    const int tid = threadIdx.x;
    const int wid = tid >> 6, lane = tid & 63;
    const int l15 = lane & 15, lk = lane >> 4;
    const int j0 = ng * NB;
    const int b0 = g * MG;
    unsigned* cnt = bars + g * 32;
    short* rhg = rhbf + (size_t)g * MG * GH;

    // persistent weight fragments: waves 0,1 -> r rows; 2,3 -> u rows; 4,5 -> c rows
    bf16x8 wB[16];
    if (wid < 6) {
        const float* wr;
        if (wid < 2)      wr = Wru + (size_t)(j0 + l15) * GH;
        else if (wid < 4) wr = Wru + (size_t)(GH + j0 + l15) * GH;
        else              wr = Wc  + (size_t)(j0 + l15) * GH;
        #pragma unroll
        for (int kt = 0; kt < 16; ++kt) {
            int ke = kt*32 + lk*8;
            float4 f0 = *(const float4*)(wr + ke);
            float4 f1 = *(const float4*)(wr + ke + 4);
            bf16x8 v;
            v[0]=f2bf(f0.x); v[1]=f2bf(f0.y); v[2]=f2bf(f0.z); v[3]=f2bf(f0.w);
            v[4]=f2bf(f1.x); v[5]=f2bf(f1.y); v[6]=f2bf(f1.z); v[7]=f2bf(f1.w);
            wB[kt] = v;
        }
    }
    {
        int row = tid >> 4, col = tid & 15;
        sHfp[row*17 + col] = gh0f[(size_t)(b0 + row)*GH + j0 + col];
    }

    for (int t = 0; t < TT; ++t) {
        const short* hsrc = hbf + (size_t)(t & 1) * BB * GH;
        short*       hdst = hbf + (size_t)((t + 1) & 1) * BB * GH;

        // stage group h -> sH (coherent)
        #pragma unroll
        for (int i = 0; i < 4; ++i) {
            int row = i*8 + wid;
            int kb  = lane << 4;
            const unsigned long long* gp =
                (const unsigned long long*)((const char*)(hsrc + (size_t)(b0 + row)*GH) + kb);
            unsigned long long v0 = ld_coh64(gp);
            unsigned long long v1 = ld_coh64(gp + 1);
            u64x2 v; v[0] = v0; v[1] = v1;
            *(u64x2*)(sH + row*1024 + (kb ^ ((row & 7) << 4))) = v;
        }
        __syncthreads();

        // phase 1 (waves 0-3): r (0,1) and u (2,3)
        if (wid < 4) {
            const int m = wid & 1;
            const int arow = m*16 + l15;
            const int asw  = (arow & 7) << 4;
            const char* hb = sH + arow*1024;
            f32x4 acc = {0.f,0.f,0.f,0.f};
            #pragma unroll
            for (int kt = 0; kt < 16; ++kt) {
                int kb = kt*64 + lk*16;
                bf16x8 a = *(const bf16x8*)(hb + (kb ^ asw));
                acc = __builtin_amdgcn_mfma_f32_16x16x32_bf16(a, wB[kt], acc, 0, 0, 0);
            }
            if (wid < 2) {
                #pragma unroll
                for (int v = 0; v < 4; ++v) {
                    int row = m*16 + lk*4 + v;
                    float hp = sHfp[row*17 + l15];
                    float rv = sigm(acc[v]);
                    unsigned* dst = (unsigned*)&rhg[(size_t)row*GH + j0 + (l15 & ~1)];
                    pack_store_bf(dst, f2bf(rv * hp), l15);
                }
            } else {
                #pragma unroll
                for (int v = 0; v < 4; ++v) {
                    int row = m*16 + lk*4 + v;
                    sU[row*17 + l15] = sigm(acc[v] + 1.0f);
                }
            }
        }
        grp_sync(cnt, (unsigned)((2*t + 1) * NGB));

        // stage rh -> sH (coherent, reuse buffer)
        #pragma unroll
        for (int i = 0; i < 4; ++i) {
            int row = i*8 + wid;
            int kb  = lane << 4;
            const unsigned long long* gp =
                (const unsigned long long*)((const char*)(rhg + (size_t)row*GH) + kb);
            unsigned long long v0 = ld_coh64(gp);
            unsigned long long v1 = ld_coh64(gp + 1);
            u64x2 v; v[0] = v0; v[1] = v1;
            *(u64x2*)(sH + row*1024 + (kb ^ ((row & 7) << 4))) = v;
        }
        __syncthreads();

        // phase 2 (waves 4,5): candidate + combine
        if (wid == 4 || wid == 5) {
            const int m = wid & 1;
            const int arow = m*16 + l15;
            const int asw  = (arow & 7) << 4;
            const char* hb = sH + arow*1024;
            f32x4 acc = {0.f,0.f,0.f,0.f};
            #pragma unroll
            for (int kt = 0; kt < 16; ++kt) {
                int kb = kt*64 + lk*16;
                bf16x8 a = *(const bf16x8*)(hb + (kb ^ asw));
                acc = __builtin_amdgcn_mfma_f32_16x16x32_bf16(a, wB[kt], acc, 0, 0, 0);
            }
            #pragma unroll
            for (int v = 0; v < 4; ++v) {
                int row = m*16 + lk*4 + v;
                float cv = tanhf(acc[v]);
                float u  = sU[row*17 + l15];
                float hp = sHfp[row*17 + l15];
                float hn = u*hp + (1.0f - u)*cv;
                sHfp[row*17 + l15] = hn;
                unsigned* dst = (unsigned*)&hdst[(size_t)(b0 + row)*GH + j0 + (l15 & ~1)];
                pack_store_bf(dst, f2bf(hn), l15);
                out[((size_t)(b0 + row)*TT + t)*GH + j0 + l15] = fminf(fmaxf(hn, -5.0f), 5.0f);
            }
        }
        grp_sync(cnt, (unsigned)((2*t + 2) * NGB));
    }
}

extern "C" void kernel_launch(void* const* d_in, const int* in_sizes, int n_in,
                              void* d_out, int out_size, void* d_ws, size_t ws_size,
                              hipStream_t stream) {
    (void)in_sizes; (void)n_in; (void)out_size; (void)ws_size;

    const float* src    = (const float*)d_in[0];
    const float* eps    = (const float*)d_in[1];
    const float* enc_Wi = (const float*)d_in[2];
    const float* enc_Wh = (const float*)d_in[3];
    const float* e2g    = (const float*)d_in[4];
    const float* gWru   = (const float*)d_in[5];
    const float* gWc    = (const float*)d_in[6];
    float* out = (float*)d_out;

    char* ws = (char*)d_ws;
    unsigned* bars = (unsigned*)ws;                          // 8 KB (enc @0, gen @+4KB)
    float* hencf = (float*)(ws + 8192);                      // 512 KB [256][512] f32
    float* gh0f  = (float*)(ws + 8192 + 512*1024);           // 512 KB [256][512] f32
    short* encH  = (short*)(ws + 8192 + 1024*1024);          // 512 KB [2][256][512] bf16
    short* genH  = (short*)(ws + 8192 + 1536*1024);          // 512 KB [2][256][512] bf16
    short* rhbf  = (short*)(ws + 8192 + 2048*1024);          // 256 KB [8][32][512] bf16

    hipMemsetAsync(bars, 0, 8192, stream);
    hipMemsetAsync(encH, 0, (size_t)BB*EH*2, stream);        // enc h0 = 0 (slot 0)

    enc_kernel<<<dim3(256), dim3(512), 0, stream>>>(src, enc_Wi, enc_Wh, encH, hencf, bars);
    ic_kernel <<<dim3(256), dim3(256), 0, stream>>>(hencf, e2g, eps,
                                                    out + (size_t)BB*TT*GH, gh0f, genH);
    gen_kernel<<<dim3(256), dim3(512), 0, stream>>>(gWru, gWc, gh0f, genH, rhbf, out,
                                                    bars + 1024);
}

// Round 4
// 4905.119 us; speedup vs baseline: 24.0844x; 1.1602x over previous
//
#include <hip/hip_runtime.h>
#include <hip/hip_bf16.h>
#include <math.h>

#define BB 256
#define TT 512
#define INW 128
#define EH 512
#define GH 512

#define NGRP 16          // batch groups
#define NGB 16           // blocks per group (column slices)
#define MG 16            // batch rows per group
#define NB 32            // output cols per block (2 x 16-col tiles)
#define FLS 16           // flag stride in u32 (64 B)

typedef __attribute__((ext_vector_type(8))) short bf16x8;
typedef __attribute__((ext_vector_type(4))) float f32x4;
typedef __attribute__((ext_vector_type(2))) unsigned long long u64x2;

__device__ __forceinline__ float sigm(float x){ return 1.0f/(1.0f+__expf(-x)); }
__device__ __forceinline__ short f2bf(float x){
    __hip_bfloat16 h = __float2bfloat16(x);
    return *reinterpret_cast<short*>(&h);
}

// IC-coherent (agent-scope, relaxed) data path: bypasses non-coherent L1/L2.
__device__ __forceinline__ unsigned long long ld_coh64(const unsigned long long* p){
    return __hip_atomic_load(p, __ATOMIC_RELAXED, __HIP_MEMORY_SCOPE_AGENT);
}
__device__ __forceinline__ void st_coh32(unsigned* p, unsigned v){
    __hip_atomic_store(p, v, __ATOMIC_RELAXED, __HIP_MEMORY_SCOPE_AGENT);
}

// Flag-based group barrier: no atomic RMW, no cache-wide fences.
// Data stores drained (vmcnt) before flag store => flag visible implies data visible.
__device__ __forceinline__ void grp_barrier(unsigned* gf, int ng, unsigned e){
    asm volatile("s_waitcnt vmcnt(0)" ::: "memory");
    __syncthreads();
    if (threadIdx.x == 0) st_coh32(gf + ng*FLS, e);
    if (threadIdx.x < 64) {
        const unsigned* p = gf + (threadIdx.x & (NGB-1)) * FLS;
        long spins = 0;
        for (;;) {
            unsigned v = __hip_atomic_load(p, __ATOMIC_RELAXED, __HIP_MEMORY_SCOPE_AGENT);
            if (__all((int)(v >= e))) break;
            if (++spins > (1L << 20)) break;   // escape hatch
        }
    }
    __syncthreads();
}

// pack this lane's bf16 (even/odd adjacent cols) into u32, even lane stores coherently
__device__ __forceinline__ void pack_store_bf(unsigned* dst_even, short bv, int l15){
    unsigned mine = (unsigned short)bv;
    unsigned othr = __shfl_xor(mine, 1);
    if (!(l15 & 1)) st_coh32(dst_even, (othr << 16) | mine);
}

// ================= ENCODER =====================================================================
__global__ __launch_bounds__(512, 1) void enc_kernel(
    const float* __restrict__ src,   // [256][512][128]
    const float* __restrict__ Wi,    // [1536][128] rows r,z,n
    const float* __restrict__ Wh,    // [1536][512]
    short*       __restrict__ hbf,   // [2][256][512] bf16 ping-pong, slot0 zeroed
    float*       __restrict__ hencf, // [256][512] f32 final state
    unsigned*    __restrict__ flags)
{
    __shared__ __align__(16) char sH[MG*1024];   // [16][512] bf16, swizzled
    __shared__ __align__(16) char sX[MG*256];    // [16][128] bf16, swizzled
    __shared__ float sR[MG*33];
    __shared__ float sZ[MG*33];
    __shared__ float sHfp[MG*33];                // private fp32 h slice [16 rows][32 cols]

    const int bid = blockIdx.x;
    const int g = bid >> 4, ng = bid & 15;
    const int tid = threadIdx.x;
    const int wid = tid >> 6, lane = tid & 63;
    const int l15 = lane & 15, lk = lane >> 4;
    const int j0 = ng * NB;
    const int b0 = g * MG;
    unsigned* gf = flags + g * NGB * FLS;

    // persistent weights: wave w<6 handles (gate = w>>1, coltile ct = w&1)
    bf16x8 whB[16], wxB[4];
    const int gate = wid >> 1, ct = wid & 1;
    const int col = ct*16 + l15;
    if (wid < 6) {
        const float* wrh = Wh + (size_t)(gate*EH + j0 + col) * EH;
        const float* wrx = Wi + (size_t)(gate*EH + j0 + col) * INW;
        #pragma unroll
        for (int kt = 0; kt < 16; ++kt) {
            int ke = kt*32 + lk*8;
            float4 f0 = *(const float4*)(wrh + ke);
            float4 f1 = *(const float4*)(wrh + ke + 4);
            bf16x8 v;
            v[0]=f2bf(f0.x); v[1]=f2bf(f0.y); v[2]=f2bf(f0.z); v[3]=f2bf(f0.w);
            v[4]=f2bf(f1.x); v[5]=f2bf(f1.y); v[6]=f2bf(f1.z); v[7]=f2bf(f1.w);
            whB[kt] = v;
        }
        #pragma unroll
        for (int kt = 0; kt < 4; ++kt) {
            int ke = kt*32 + lk*8;
            float4 f0 = *(const float4*)(wrx + ke);
            float4 f1 = *(const float4*)(wrx + ke + 4);
            bf16x8 v;
            v[0]=f2bf(f0.x); v[1]=f2bf(f0.y); v[2]=f2bf(f0.z); v[3]=f2bf(f0.w);
            v[4]=f2bf(f1.x); v[5]=f2bf(f1.y); v[6]=f2bf(f1.z); v[7]=f2bf(f1.w);
            wxB[kt] = v;
        }
    }
    sHfp[(tid >> 5)*33 + (tid & 31)] = 0.0f;     // 512 threads cover 16x32

    for (int t = 0; t < TT; ++t) {
        const short* hsrc = hbf + (size_t)(t & 1) * BB * EH;
        short*       hdst = hbf + (size_t)((t + 1) & 1) * BB * EH;

        // stage group h (bf16) -> sH: coherent loads, swizzled LDS write (2 chunks/thread)
        #pragma unroll
        for (int i = 0; i < 2; ++i) {
            int c = i*512 + tid;
            int row = c >> 6;
            int kb  = (c & 63) << 4;
            const unsigned long long* gp =
                (const unsigned long long*)((const char*)(hsrc + (size_t)(b0 + row)*EH) + kb);
            unsigned long long v0 = ld_coh64(gp);
            unsigned long long v1 = ld_coh64(gp + 1);
            u64x2 v; v[0] = v0; v[1] = v1;
            *(u64x2*)(sH + row*1024 + (kb ^ ((row & 7) << 4))) = v;
        }
        // stage x tile fp32->bf16 (threads 0..255)
        if (tid < 256) {
            int row = tid >> 4, k = (tid & 15) * 8;
            const float* sp = src + ((size_t)(b0 + row)*TT + t)*INW + k;
            float4 f0 = *(const float4*)sp;
            float4 f1 = *(const float4*)(sp + 4);
            bf16x8 v;
            v[0]=f2bf(f0.x); v[1]=f2bf(f0.y); v[2]=f2bf(f0.z); v[3]=f2bf(f0.w);
            v[4]=f2bf(f1.x); v[5]=f2bf(f1.y); v[6]=f2bf(f1.z); v[7]=f2bf(f1.w);
            *(bf16x8*)(sX + row*256 + ((k*2) ^ ((row & 7) << 4))) = v;
        }
        __syncthreads();

        f32x4 acc0 = {0.f,0.f,0.f,0.f}, acc1 = {0.f,0.f,0.f,0.f};
        f32x4 accx = {0.f,0.f,0.f,0.f};
        if (wid < 6) {
            const int asw = (l15 & 7) << 4;
            const char* hb = sH + l15*1024;
            const char* xb = sX + l15*256;
            #pragma unroll
            for (int kt = 0; kt < 8; ++kt) {
                int kb = kt*64 + lk*16;
                bf16x8 a = *(const bf16x8*)(hb + (kb ^ asw));
                acc0 = __builtin_amdgcn_mfma_f32_16x16x32_bf16(a, whB[kt], acc0, 0, 0, 0);
            }
            #pragma unroll
            for (int kt = 8; kt < 16; ++kt) {
                int kb = kt*64 + lk*16;
                bf16x8 a = *(const bf16x8*)(hb + (kb ^ asw));
                acc1 = __builtin_amdgcn_mfma_f32_16x16x32_bf16(a, whB[kt], acc1, 0, 0, 0);
            }
            #pragma unroll
            for (int kt = 0; kt < 4; ++kt) {
                int kb = kt*64 + lk*16;
                bf16x8 a = *(const bf16x8*)(xb + (kb ^ asw));
                accx = __builtin_amdgcn_mfma_f32_16x16x32_bf16(a, wxB[kt], accx, 0, 0, 0);
            }
        }
        f32x4 acch = acc0 + acc1;
        if (wid < 2) {          // r gate
            #pragma unroll
            for (int v = 0; v < 4; ++v)
                sR[(lk*4 + v)*33 + col] = sigm(accx[v] + acch[v]);
        } else if (wid < 4) {   // z gate
            #pragma unroll
            for (int v = 0; v < 4; ++v)
                sZ[(lk*4 + v)*33 + col] = sigm(accx[v] + acch[v]);
        }
        __syncthreads();
        if (wid == 4 || wid == 5) {   // n gate + combine + coherent packed store
            #pragma unroll
            for (int v = 0; v < 4; ++v) {
                int row = lk*4 + v;
                float r  = sR[row*33 + col];
                float z  = sZ[row*33 + col];
                float n  = tanhf(accx[v] + r * acch[v]);
                float hp = sHfp[row*33 + col];
                float hn = (1.f - z)*n + z*hp;
                sHfp[row*33 + col] = hn;
                unsigned* dst = (unsigned*)&hdst[(size_t)(b0 + row)*EH + j0 + ct*16 + (l15 & ~1)];
                pack_store_bf(dst, f2bf(hn), l15);
                if (t == TT - 1) hencf[(size_t)(b0 + row)*EH + j0 + col] = hn;
            }
        }
        grp_barrier(gf, ng, (unsigned)(t + 1));
    }
}

// ================= enc2gen linear + reparameterized IC sample =================================
__global__ __launch_bounds__(256) void ic_kernel(
    const float* __restrict__ henc,    // [256][512]
    const float* __restrict__ W,       // [1024][512]
    const float* __restrict__ eps,     // [256][512]
    float*       __restrict__ out_icp, // [256][1024] (output #2)
    float*       __restrict__ gh0f,    // [256][512] f32 generator IC
    short*       __restrict__ gh0b)    // [256][512] bf16 mirror (genH slot0)
{
    __shared__ float hb[EH];
    const int b = blockIdx.x, tid = threadIdx.x;
    for (int k = tid; k < EH; k += 256) hb[k] = henc[(size_t)b*EH + k];
    __syncthreads();

    for (int jj = tid; jj < GH; jj += 256) {
        const float4* wm = (const float4*)(W + (size_t)jj * EH);
        const float4* wl = (const float4*)(W + (size_t)(GH + jj) * EH);
        float am = 0.f, al = 0.f;
        #pragma unroll 4
        for (int k4 = 0; k4 < EH/4; ++k4) {
            float4 h = ((const float4*)hb)[k4];
            float4 a = wm[k4], c = wl[k4];
            am += h.x*a.x + h.y*a.y + h.z*a.z + h.w*a.w;
            al += h.x*c.x + h.y*c.y + h.z*c.z + h.w*c.w;
        }
        out_icp[(size_t)b*2*GH + jj]      = am;
        out_icp[(size_t)b*2*GH + GH + jj] = al;
        float icv = am + __expf(0.5f * al) * eps[(size_t)b*GH + jj];
        gh0f[(size_t)b*GH + jj] = icv;
        gh0b[(size_t)b*GH + jj] = f2bf(icv);
    }
}

// ================= GENERATOR ===================================================================
__global__ __launch_bounds__(512, 1) void gen_kernel(
    const float* __restrict__ Wru,   // [1024][512] rows r then u
    const float* __restrict__ Wc,    // [512][512]
    const float* __restrict__ gh0f,  // [256][512] f32 ic
    short*       __restrict__ hbf,   // [2][256][512] bf16 ping-pong (slot0 = ic mirror)
    short*       __restrict__ rhbf,  // [16][16][512] bf16 r*h exchange
    float*       __restrict__ out,   // [256][512][512] (output #1)
    unsigned*    __restrict__ flags)
{
    __shared__ __align__(16) char sH[MG*1024];   // h or rh tile [16][512] bf16, swizzled
    __shared__ float sU[MG*33];
    __shared__ float sHfp[MG*33];

    const int bid = blockIdx.x;
    const int g = bid >> 4, ng = bid & 15;
    const int tid = threadIdx.x;
    const int wid = tid >> 6, lane = tid & 63;
    const int l15 = lane & 15, lk = lane >> 4;
    const int j0 = ng * NB;
    const int b0 = g * MG;
    unsigned* gf = flags + g * NGB * FLS;
    short* rhg = rhbf + (size_t)g * MG * GH;

    // persistent weights: wave w<6 handles (gate = w>>1 [0=r,1=u,2=c], coltile ct = w&1)
    bf16x8 wB[16];
    const int gate = wid >> 1, ct = wid & 1;
    const int col = ct*16 + l15;
    if (wid < 6) {
        const float* wr;
        if (gate == 0)      wr = Wru + (size_t)(j0 + col) * GH;
        else if (gate == 1) wr = Wru + (size_t)(GH + j0 + col) * GH;
        else                wr = Wc  + (size_t)(j0 + col) * GH;
        #pragma unroll
        for (int kt = 0; kt < 16; ++kt) {
            int ke = kt*32 + lk*8;
            float4 f0 = *(const float4*)(wr + ke);
            float4 f1 = *(const float4*)(wr + ke + 4);
            bf16x8 v;
            v[0]=f2bf(f0.x); v[1]=f2bf(f0.y); v[2]=f2bf(f0.z); v[3]=f2bf(f0.w);
            v[4]=f2bf(f1.x); v[5]=f2bf(f1.y); v[6]=f2bf(f1.z); v[7]=f2bf(f1.w);
            wB[kt] = v;
        }
    }
    {   // private fp32 h slice init from ic (16 rows x 32 cols)
        int row = tid >> 5, c = tid & 31;
        sHfp[row*33 + c] = gh0f[(size_t)(b0 + row)*GH + j0 + c];
    }

    for (int t = 0; t < TT; ++t) {
        const short* hsrc = hbf + (size_t)(t & 1) * BB * GH;
        short*       hdst = hbf + (size_t)((t + 1) & 1) * BB * GH;

        // stage group h -> sH (coherent, 2 chunks/thread)
        #pragma unroll
        for (int i = 0; i < 2; ++i) {
            int c = i*512 + tid;
            int row = c >> 6;
            int kb  = (c & 63) << 4;
            const unsigned long long* gp =
                (const unsigned long long*)((const char*)(hsrc + (size_t)(b0 + row)*GH) + kb);
            unsigned long long v0 = ld_coh64(gp);
            unsigned long long v1 = ld_coh64(gp + 1);
            u64x2 v; v[0] = v0; v[1] = v1;
            *(u64x2*)(sH + row*1024 + (kb ^ ((row & 7) << 4))) = v;
        }
        __syncthreads();

        // phase 1: waves 0,1 -> r; waves 2,3 -> u
        if (wid < 4) {
            const int asw = (l15 & 7) << 4;
            const char* hb = sH + l15*1024;
            f32x4 acc0 = {0.f,0.f,0.f,0.f}, acc1 = {0.f,0.f,0.f,0.f};
            #pragma unroll
            for (int kt = 0; kt < 8; ++kt) {
                int kb = kt*64 + lk*16;
                bf16x8 a = *(const bf16x8*)(hb + (kb ^ asw));
                acc0 = __builtin_amdgcn_mfma_f32_16x16x32_bf16(a, wB[kt], acc0, 0, 0, 0);
            }
            #pragma unroll
            for (int kt = 8; kt < 16; ++kt) {
                int kb = kt*64 + lk*16;
                bf16x8 a = *(const bf16x8*)(hb + (kb ^ asw));
                acc1 = __builtin_amdgcn_mfma_f32_16x16x32_bf16(a, wB[kt], acc1, 0, 0, 0);
            }
            f32x4 acc = acc0 + acc1;
            if (wid < 2) {
                #pragma unroll
                for (int v = 0; v < 4; ++v) {
                    int row = lk*4 + v;
                    float hp = sHfp[row*33 + col];
                    float rv = sigm(acc[v]);
                    unsigned* dst = (unsigned*)&rhg[(size_t)row*GH + j0 + ct*16 + (l15 & ~1)];
                    pack_store_bf(dst, f2bf(rv * hp), l15);
                }
            } else {
                #pragma unroll
                for (int v = 0; v < 4; ++v)
                    sU[(lk*4 + v)*33 + col] = sigm(acc[v] + 1.0f);
            }
        }
        grp_barrier(gf, ng, (unsigned)(2*t + 1));

        // stage rh -> sH (coherent, reuse buffer)
        #pragma unroll
        for (int i = 0; i < 2; ++i) {
            int c = i*512 + tid;
            int row = c >> 6;
            int kb  = (c & 63) << 4;
            const unsigned long long* gp =
                (const unsigned long long*)((const char*)(rhg + (size_t)row*GH) + kb);
            unsigned long long v0 = ld_coh64(gp);
            unsigned long long v1 = ld_coh64(gp + 1);
            u64x2 v; v[0] = v0; v[1] = v1;
            *(u64x2*)(sH + row*1024 + (kb ^ ((row & 7) << 4))) = v;
        }
        __syncthreads();

        // phase 2: waves 4,5 -> candidate + combine
        if (wid == 4 || wid == 5) {
            const int asw = (l15 & 7) << 4;
            const char* hb = sH + l15*1024;
            f32x4 acc0 = {0.f,0.f,0.f,0.f}, acc1 = {0.f,0.f,0.f,0.f};
            #pragma unroll
            for (int kt = 0; kt < 8; ++kt) {
                int kb = kt*64 + lk*16;
                bf16x8 a = *(const bf16x8*)(hb + (kb ^ asw));
                acc0 = __builtin_amdgcn_mfma_f32_16x16x32_bf16(a, wB[kt], acc0, 0, 0, 0);
            }
            #pragma unroll
            for (int kt = 8; kt < 16; ++kt) {
                int kb = kt*64 + lk*16;
                bf16x8 a = *(const bf16x8*)(hb + (kb ^ asw));
                acc1 = __builtin_amdgcn_mfma_f32_16x16x32_bf16(a, wB[kt], acc1, 0, 0, 0);
            }
            f32x4 acc = acc0 + acc1;
            #pragma unroll
            for (int v = 0; v < 4; ++v) {
                int row = lk*4 + v;
                float cv = tanhf(acc[v]);
                float u  = sU[row*33 + col];
                float hp = sHfp[row*33 + col];
                float hn = u*hp + (1.0f - u)*cv;
                sHfp[row*33 + col] = hn;
                unsigned* dst = (unsigned*)&hdst[(size_t)(b0 + row)*GH + j0 + ct*16 + (l15 & ~1)];
                pack_store_bf(dst, f2bf(hn), l15);
                out[((size_t)(b0 + row)*TT + t)*GH + j0 + col] = fminf(fmaxf(hn, -5.0f), 5.0f);
            }
        }
        grp_barrier(gf, ng, (unsigned)(2*t + 2));
    }
}

extern "C" void kernel_launch(void* const* d_in, const int* in_sizes, int n_in,
                              void* d_out, int out_size, void* d_ws, size_t ws_size,
                              hipStream_t stream) {
    (void)in_sizes; (void)n_in; (void)out_size; (void)ws_size;

    const float* src    = (const float*)d_in[0];
    const float* eps    = (const float*)d_in[1];
    const float* enc_Wi = (const float*)d_in[2];
    const float* enc_Wh = (const float*)d_in[3];
    const float* e2g    = (const float*)d_in[4];
    const float* gWru   = (const float*)d_in[5];
    const float* gWc    = (const float*)d_in[6];
    float* out = (float*)d_out;

    char* ws = (char*)d_ws;
    unsigned* encFl = (unsigned*)ws;                         // 16 KB: 16 grp x 16 flags x 64B
    unsigned* genFl = (unsigned*)(ws + 16384);               // 16 KB
    float* hencf = (float*)(ws + 32768);                     // 512 KB [256][512] f32
    float* gh0f  = (float*)(ws + 32768 + 512*1024);          // 512 KB [256][512] f32
    short* encH  = (short*)(ws + 32768 + 1024*1024);         // 512 KB [2][256][512] bf16
    short* genH  = (short*)(ws + 32768 + 1536*1024);         // 512 KB [2][256][512] bf16
    short* rhbf  = (short*)(ws + 32768 + 2048*1024);         // 256 KB [16][16][512] bf16

    hipMemsetAsync(ws, 0, 32768, stream);                    // flags = 0
    hipMemsetAsync(encH, 0, (size_t)BB*EH*2, stream);        // enc h0 = 0 (slot 0)

    enc_kernel<<<dim3(256), dim3(512), 0, stream>>>(src, enc_Wi, enc_Wh, encH, hencf, encFl);
    ic_kernel <<<dim3(256), dim3(256), 0, stream>>>(hencf, e2g, eps,
                                                    out + (size_t)BB*TT*GH, gh0f, genH);
    gen_kernel<<<dim3(256), dim3(512), 0, stream>>>(gWru, gWc, gh0f, genH, rhbf, out,
                                                    genFl);
}